// Round 1
// baseline (1305.042 us; speedup 1.0000x reference)
//
#include <hip/hip_runtime.h>
#include <math.h>

#define NN 100000
#define NE 3200000
#define NG 1024
#define FDIM 128
#define NFC1 64
#define NFC2 10
#define SCAN_BLOCKS 98  // ceil(NN/1024)

// ---------------- CSR build ----------------
__global__ __launch_bounds__(256) void hist_kernel(const int* __restrict__ dst,
                                                   int* __restrict__ counts) {
  int e = blockIdx.x * 256 + threadIdx.x;
  if (e < NE) atomicAdd(&counts[dst[e]], 1);
}

__global__ __launch_bounds__(256) void scan_reduce(const int* __restrict__ counts,
                                                   int* __restrict__ bsum) {
  __shared__ int s[256];
  int b = blockIdx.x, t = threadIdx.x;
  int i0 = b * 1024 + t * 4;
  int sum = 0;
#pragma unroll
  for (int j = 0; j < 4; ++j) {
    int i = i0 + j;
    sum += (i < NN) ? counts[i] : 0;
  }
  s[t] = sum;
  __syncthreads();
  for (int st = 128; st > 0; st >>= 1) {
    if (t < st) s[t] += s[t + st];
    __syncthreads();
  }
  if (t == 0) bsum[b] = s[0];
}

__global__ __launch_bounds__(128) void scan_bsum(const int* __restrict__ bsum,
                                                 int* __restrict__ bsum2) {
  __shared__ int s[128];
  int t = threadIdx.x;
  s[t] = (t < SCAN_BLOCKS) ? bsum[t] : 0;
  __syncthreads();
  for (int st = 1; st < 128; st <<= 1) {
    int v = (t >= st) ? s[t - st] : 0;
    __syncthreads();
    s[t] += v;
    __syncthreads();
  }
  if (t < SCAN_BLOCKS) bsum2[t] = s[t];
}

__global__ __launch_bounds__(256) void scan_write(const int* __restrict__ counts,
                                                  const int* __restrict__ bsum2,
                                                  int* __restrict__ row_off,
                                                  int* __restrict__ cursor) {
  __shared__ int s[256];
  int b = blockIdx.x, t = threadIdx.x;
  int i0 = b * 1024 + t * 4;
  int c[4];
  int p = 0;
#pragma unroll
  for (int j = 0; j < 4; ++j) {
    int i = i0 + j;
    c[j] = (i < NN) ? counts[i] : 0;
    p += c[j];
  }
  s[t] = p;
  __syncthreads();
  for (int st = 1; st < 256; st <<= 1) {
    int v = (t >= st) ? s[t - st] : 0;
    __syncthreads();
    s[t] += v;
    __syncthreads();
  }
  int base = (b > 0 ? bsum2[b - 1] : 0) + s[t] - p;  // exclusive prefix for item i0
#pragma unroll
  for (int j = 0; j < 4; ++j) {
    int i = i0 + j;
    if (i < NN) {
      cursor[i] = base;
      row_off[i + 1] = base + c[j];
    }
    base += c[j];
  }
  if (b == 0 && t == 0) row_off[0] = 0;
}

__global__ __launch_bounds__(256) void scatter_kernel(const int* __restrict__ src,
                                                      const int* __restrict__ dst,
                                                      int* __restrict__ cursor,
                                                      int* __restrict__ esrc) {
  int e = blockIdx.x * 256 + threadIdx.x;
  if (e < NE) {
    int d = dst[e];
    int p = atomicAdd(&cursor[d], 1);
    esrc[p] = src[e];
  }
}

// ---------------- edge aggregation (CSR gather) ----------------
// One wave per node. Lanes split into two halves; each half streams one edge's
// 512B row as 32 x float4. Halves combined by shfl at the end.
__global__ __launch_bounds__(256) void agg_csr(const float4* __restrict__ xin,
                                               const int* __restrict__ row_off,
                                               const int* __restrict__ esrc,
                                               float4* __restrict__ aggout) {
  int node = blockIdx.x * 4 + (threadIdx.x >> 6);
  int lane = threadIdx.x & 63;
  int half = lane >> 5;
  int l32 = lane & 31;
  int beg = row_off[node];
  int end = row_off[node + 1];
  float4 acc = make_float4(0.f, 0.f, 0.f, 0.f);
  int e = beg + half;
  for (; e + 2 < end; e += 4) {  // 2 edges per half in flight
    int i0 = esrc[e];
    int i1 = esrc[e + 2];
    float4 v0 = xin[(size_t)i0 * 32 + l32];
    float4 v1 = xin[(size_t)i1 * 32 + l32];
    acc.x += v0.x + v1.x;
    acc.y += v0.y + v1.y;
    acc.z += v0.z + v1.z;
    acc.w += v0.w + v1.w;
  }
  for (; e < end; e += 2) {
    int i0 = esrc[e];
    float4 v0 = xin[(size_t)i0 * 32 + l32];
    acc.x += v0.x;
    acc.y += v0.y;
    acc.z += v0.z;
    acc.w += v0.w;
  }
  acc.x += __shfl_down(acc.x, 32, 64);
  acc.y += __shfl_down(acc.y, 32, 64);
  acc.z += __shfl_down(acc.z, 32, 64);
  acc.w += __shfl_down(acc.w, 32, 64);
  if (half == 0) aggout[(size_t)node * 32 + l32] = acc;
}

// ---------------- fp32 GEMM: out = relu(A[NN,128] @ W[128,128] + bias) ----------------
// Block: 256 thr, 64 rows. A-tile transposed in LDS (stride 68 -> conflict-free
// staging writes, 16B-aligned broadcast b128 reads). W streamed from L1/L2 as
// per-lane float4. Lane tile: 8 rows x 4 cols.
__global__ __launch_bounds__(256) void gemm_bias_relu(const float* __restrict__ A,
                                                      const float* __restrict__ W,
                                                      const float* __restrict__ bias,
                                                      float* __restrict__ out) {
  __shared__ __align__(16) float aT[128 * 68];
  int t = threadIdx.x;
  int rowbase = blockIdx.x * 64;

  {  // stage 64 rows x 128 k, transposed
    int r = t >> 2;   // 0..63
    int kq = t & 3;   // 0..3
    bool valid = (rowbase + r) < NN;
    const float* Arow = A + (size_t)(rowbase + r) * FDIM;
#pragma unroll
    for (int q = 0; q < 8; ++q) {
      int k0 = kq * 4 + q * 16;
      float4 v = valid ? *(const float4*)(Arow + k0) : make_float4(0.f, 0.f, 0.f, 0.f);
      aT[(k0 + 0) * 68 + r] = v.x;
      aT[(k0 + 1) * 68 + r] = v.y;
      aT[(k0 + 2) * 68 + r] = v.z;
      aT[(k0 + 3) * 68 + r] = v.w;
    }
  }
  __syncthreads();

  int w = t >> 6;          // wave 0..3
  int lane = t & 63;
  int rg = lane >> 5;      // row group 0..1
  int c = lane & 31;       // col lane: cols 4c..4c+3
  int rbase = w * 16 + rg * 8;

  float acc[8][4];
#pragma unroll
  for (int r = 0; r < 8; ++r)
#pragma unroll
    for (int j = 0; j < 4; ++j) acc[r][j] = 0.f;

#pragma unroll 4
  for (int k = 0; k < 128; ++k) {
    float4 bv = *(const float4*)(W + k * FDIM + c * 4);
    const float* ap = &aT[k * 68 + rbase];
    float4 a0 = *(const float4*)(ap);
    float4 a1 = *(const float4*)(ap + 4);
    float ar[8] = {a0.x, a0.y, a0.z, a0.w, a1.x, a1.y, a1.z, a1.w};
#pragma unroll
    for (int r = 0; r < 8; ++r) {
      acc[r][0] += ar[r] * bv.x;
      acc[r][1] += ar[r] * bv.y;
      acc[r][2] += ar[r] * bv.z;
      acc[r][3] += ar[r] * bv.w;
    }
  }

  float4 b4 = *(const float4*)(bias + c * 4);
#pragma unroll
  for (int r = 0; r < 8; ++r) {
    int row = rowbase + rbase + r;
    if (row < NN) {
      float4 o;
      o.x = fmaxf(acc[r][0] + b4.x, 0.f);
      o.y = fmaxf(acc[r][1] + b4.y, 0.f);
      o.z = fmaxf(acc[r][2] + b4.z, 0.f);
      o.w = fmaxf(acc[r][3] + b4.w, 0.f);
      *(float4*)(out + (size_t)row * FDIM + c * 4) = o;
    }
  }
}

// ---------------- global sum pool (batching is sorted) ----------------
__device__ int lower_bound_dev(const int* __restrict__ arr, int n, int val) {
  int lo = 0, hi = n;
  while (lo < hi) {
    int mid = (lo + hi) >> 1;
    if (arr[mid] < val) lo = mid + 1; else hi = mid;
  }
  return lo;
}

__global__ __launch_bounds__(128) void pool_kernel(const float* __restrict__ x,
                                                   const int* __restrict__ batching,
                                                   float* __restrict__ g) {
  __shared__ int se, ee;
  int gid = blockIdx.x, t = threadIdx.x;
  if (t == 0) {
    se = lower_bound_dev(batching, NN, gid);
    ee = lower_bound_dev(batching, NN, gid + 1);
  }
  __syncthreads();
  float acc = 0.f;
  for (int n = se; n < ee; ++n) acc += x[(size_t)n * FDIM + t];
  g[(size_t)gid * FDIM + t] = acc;
}

// ---------------- FC1 + FC2 + softmax ----------------
__global__ __launch_bounds__(64) void head_kernel(const float* __restrict__ g,
                                                  const float* __restrict__ Wf1,
                                                  const float* __restrict__ bf1,
                                                  const float* __restrict__ Wf2,
                                                  const float* __restrict__ bf2,
                                                  float* __restrict__ out) {
  __shared__ float gl[128];
  __shared__ float hl[64];
  __shared__ float ol[10];
  __shared__ float red[2];
  int gid = blockIdx.x, t = threadIdx.x;
  gl[t] = g[(size_t)gid * FDIM + t];
  gl[t + 64] = g[(size_t)gid * FDIM + 64 + t];
  __syncthreads();
  float h = bf1[t];
  for (int f = 0; f < 128; ++f) h += gl[f] * Wf1[f * NFC1 + t];
  hl[t] = h;
  __syncthreads();
  if (t < NFC2) {
    float o = bf2[t];
    for (int i = 0; i < NFC1; ++i) o += hl[i] * Wf2[i * NFC2 + t];
    ol[t] = o;
  }
  __syncthreads();
  if (t == 0) {
    float m = ol[0];
    for (int i = 1; i < NFC2; ++i) m = fmaxf(m, ol[i]);
    float s = 0.f;
    for (int i = 0; i < NFC2; ++i) s += expf(ol[i] - m);
    red[0] = m;
    red[1] = s;
  }
  __syncthreads();
  if (t < NFC2) out[(size_t)gid * NFC2 + t] = expf(ol[t] - red[0]) / red[1];
}

extern "C" void kernel_launch(void* const* d_in, const int* in_sizes, int n_in,
                              void* d_out, int out_size, void* d_ws, size_t ws_size,
                              hipStream_t stream) {
  const float* node_attr = (const float*)d_in[0];
  const float* Wc = (const float*)d_in[1];   // [3][128][128]
  const float* bc = (const float*)d_in[2];   // [3][128]
  const float* Wf1 = (const float*)d_in[3];  // [128][64]
  const float* bf1 = (const float*)d_in[4];
  const float* Wf2 = (const float*)d_in[5];  // [64][10]
  const float* bf2 = (const float*)d_in[6];
  const int* src = (const int*)d_in[7];
  const int* dst = (const int*)d_in[8];
  const int* batching = (const int*)d_in[9];
  float* out = (float*)d_out;

  // workspace carve-up (~117 MB total)
  char* wsp = (char*)d_ws;
  size_t off = 0;
  auto alloc = [&](size_t bytes) -> void* {
    void* p = wsp + off;
    off += (bytes + 255) & ~(size_t)255;
    return p;
  };
  int* counts = (int*)alloc((size_t)NN * sizeof(int));
  int* cursor = (int*)alloc((size_t)NN * sizeof(int));
  int* row_off = (int*)alloc((size_t)(NN + 1) * sizeof(int));
  int* bsum = (int*)alloc(128 * sizeof(int));
  int* bsum2 = (int*)alloc(128 * sizeof(int));
  int* esrc = (int*)alloc((size_t)NE * sizeof(int));
  float* bufA = (float*)alloc((size_t)NN * FDIM * sizeof(float));
  float* bufB = (float*)alloc((size_t)NN * FDIM * sizeof(float));
  float* gbuf = (float*)alloc((size_t)NG * FDIM * sizeof(float));

  // CSR build (once; reused by all 3 layers)
  hipMemsetAsync(counts, 0, (size_t)NN * sizeof(int), stream);
  hist_kernel<<<(NE + 255) / 256, 256, 0, stream>>>(dst, counts);
  scan_reduce<<<SCAN_BLOCKS, 256, 0, stream>>>(counts, bsum);
  scan_bsum<<<1, 128, 0, stream>>>(bsum, bsum2);
  scan_write<<<SCAN_BLOCKS, 256, 0, stream>>>(counts, bsum2, row_off, cursor);
  scatter_kernel<<<(NE + 255) / 256, 256, 0, stream>>>(src, dst, cursor, esrc);

  // conv layers
  agg_csr<<<NN / 4, 256, 0, stream>>>((const float4*)node_attr, row_off, esrc, (float4*)bufB);
  gemm_bias_relu<<<(NN + 63) / 64, 256, 0, stream>>>(bufB, Wc, bc, bufA);
  agg_csr<<<NN / 4, 256, 0, stream>>>((const float4*)bufA, row_off, esrc, (float4*)bufB);
  gemm_bias_relu<<<(NN + 63) / 64, 256, 0, stream>>>(bufB, Wc + 16384, bc + 128, bufA);
  agg_csr<<<NN / 4, 256, 0, stream>>>((const float4*)bufA, row_off, esrc, (float4*)bufB);
  gemm_bias_relu<<<(NN + 63) / 64, 256, 0, stream>>>(bufB, Wc + 32768, bc + 256, bufA);

  // pool + head
  pool_kernel<<<NG, 128, 0, stream>>>(bufA, batching, gbuf);
  head_kernel<<<NG, 64, 0, stream>>>(gbuf, Wf1, bf1, Wf2, bf2, out);
}

// Round 2
// 1030.780 us; speedup vs baseline: 1.2661x; 1.2661x over previous
//
#include <hip/hip_runtime.h>
#include <math.h>

#define NN 100000
#define NE 3200000
#define NG 1024
#define FDIM 128
#define NFC1 64
#define NFC2 10

#define BSHIFT 9
#define NBUCK 196   // ceil(NN/512)
#define CAP 20480   // mean 16384, sigma ~127 -> 32-sigma headroom
#define EPB 16      // edges per thread in bin_kernel

// ---------------- pass 1: bin edges into 196 coarse buckets ----------------
// Packed value: (dst & 511) << 17 | src   (src < 2^17, dst_local < 2^9)
__global__ __launch_bounds__(256) void bin_kernel(const int* __restrict__ src,
                                                  const int* __restrict__ dst,
                                                  int* __restrict__ gcursor,
                                                  int* __restrict__ staging) {
  __shared__ int hist[NBUCK];
  __shared__ int base[NBUCK];
  int t = threadIdx.x;
  for (int i = t; i < NBUCK; i += 256) hist[i] = 0;
  __syncthreads();
  size_t e0 = (size_t)blockIdx.x * (256 * EPB);
  int bk[EPB], rank[EPB], val[EPB];
#pragma unroll
  for (int j = 0; j < EPB; ++j) {
    size_t e = e0 + (size_t)j * 256 + t;
    if (e < NE) {
      int d = dst[e];
      int s = src[e];
      bk[j] = d >> BSHIFT;
      val[j] = ((d & 511) << 17) | s;
      rank[j] = atomicAdd(&hist[bk[j]], 1);
    } else {
      bk[j] = -1;
    }
  }
  __syncthreads();
  for (int i = t; i < NBUCK; i += 256) base[i] = atomicAdd(&gcursor[i], hist[i]);
  __syncthreads();
#pragma unroll
  for (int j = 0; j < EPB; ++j) {
    if (bk[j] >= 0) {
      int pos = base[bk[j]] + rank[j];
      if (pos < CAP) staging[(size_t)bk[j] * CAP + pos] = val[j];
    }
  }
}

// ---------------- pass 1.5: exclusive scan of bucket counts ----------------
__global__ __launch_bounds__(256) void bucket_scan(const int* __restrict__ gcursor,
                                                   int* __restrict__ bbase) {
  __shared__ int s[256];
  int t = threadIdx.x;
  int v = (t < NBUCK) ? gcursor[t] : 0;
  s[t] = v;
  __syncthreads();
  for (int st = 1; st < 256; st <<= 1) {
    int u = (t >= st) ? s[t - st] : 0;
    __syncthreads();
    s[t] += u;
    __syncthreads();
  }
  if (t < NBUCK) bbase[t] = s[t] - v;  // exclusive
}

// ---------------- pass 2: per-bucket CSR finalize ----------------
__global__ __launch_bounds__(256) void build_kernel(const int* __restrict__ staging,
                                                    const int* __restrict__ gcursor,
                                                    const int* __restrict__ bbase,
                                                    int* __restrict__ row_off,
                                                    int* __restrict__ esrc) {
  __shared__ int ncnt[512];
  __shared__ int noff[513];
  __shared__ int part[256];
  int b = blockIdx.x, t = threadIdx.x;
  int cnt = gcursor[b];
  int ebase = bbase[b];
  int nbase = b << BSHIFT;
  ncnt[t] = 0;
  ncnt[t + 256] = 0;
  __syncthreads();
  const int* sp = staging + (size_t)b * CAP;
  for (int i = t; i < cnt; i += 256) {
    int dl = sp[i] >> 17;
    atomicAdd(&ncnt[dl], 1);
  }
  __syncthreads();
  int a0 = ncnt[2 * t], a1 = ncnt[2 * t + 1];
  part[t] = a0 + a1;
  __syncthreads();
  for (int st = 1; st < 256; st <<= 1) {
    int u = (t >= st) ? part[t - st] : 0;
    __syncthreads();
    part[t] += u;
    __syncthreads();
  }
  int excl = (t > 0) ? part[t - 1] : 0;
  noff[2 * t] = excl;
  noff[2 * t + 1] = excl + a0;
  if (t == 255) noff[512] = part[255];
  __syncthreads();
  for (int i = t; i <= 512; i += 256) {
    int n = nbase + i;
    if (n <= NN) row_off[n] = ebase + noff[i];
  }
  // reuse ncnt as write cursors
  ncnt[2 * t] = noff[2 * t];
  ncnt[2 * t + 1] = noff[2 * t + 1];
  __syncthreads();
  for (int i = t; i < cnt; i += 256) {
    int v = sp[i];
    int dl = v >> 17;
    int pos = atomicAdd(&ncnt[dl], 1);
    esrc[ebase + pos] = v & 0x1FFFF;
  }
}

// ---------------- edge aggregation (CSR gather) ----------------
// One wave per node; 2 half-waves each stream one edge row (32 x float4),
// 4 edges in flight per half. Halves combined via shfl.
__global__ __launch_bounds__(256) void agg_csr(const float4* __restrict__ xin,
                                               const int* __restrict__ row_off,
                                               const int* __restrict__ esrc,
                                               float4* __restrict__ aggout) {
  int node = blockIdx.x * 4 + (threadIdx.x >> 6);
  int lane = threadIdx.x & 63;
  int half = lane >> 5;
  int l32 = lane & 31;
  int beg = row_off[node];
  int end = row_off[node + 1];
  float4 acc = make_float4(0.f, 0.f, 0.f, 0.f);
  int e = beg + half;
  for (; e + 6 < end; e += 8) {
    int i0 = esrc[e];
    int i1 = esrc[e + 2];
    int i2 = esrc[e + 4];
    int i3 = esrc[e + 6];
    float4 v0 = xin[(size_t)i0 * 32 + l32];
    float4 v1 = xin[(size_t)i1 * 32 + l32];
    float4 v2 = xin[(size_t)i2 * 32 + l32];
    float4 v3 = xin[(size_t)i3 * 32 + l32];
    acc.x += (v0.x + v1.x) + (v2.x + v3.x);
    acc.y += (v0.y + v1.y) + (v2.y + v3.y);
    acc.z += (v0.z + v1.z) + (v2.z + v3.z);
    acc.w += (v0.w + v1.w) + (v2.w + v3.w);
  }
  for (; e < end; e += 2) {
    int i0 = esrc[e];
    float4 v0 = xin[(size_t)i0 * 32 + l32];
    acc.x += v0.x;
    acc.y += v0.y;
    acc.z += v0.z;
    acc.w += v0.w;
  }
  acc.x += __shfl_down(acc.x, 32, 64);
  acc.y += __shfl_down(acc.y, 32, 64);
  acc.z += __shfl_down(acc.z, 32, 64);
  acc.w += __shfl_down(acc.w, 32, 64);
  if (half == 0) aggout[(size_t)node * 32 + l32] = acc;
}

// ---------------- fp32 GEMM: out = relu(A[NN,128] @ W[128,128] + bias) ----------------
__global__ __launch_bounds__(256) void gemm_bias_relu(const float* __restrict__ A,
                                                      const float* __restrict__ W,
                                                      const float* __restrict__ bias,
                                                      float* __restrict__ out) {
  __shared__ __align__(16) float aT[128 * 68];
  int t = threadIdx.x;
  int rowbase = blockIdx.x * 64;

  {  // stage 64 rows x 128 k, transposed
    int r = t >> 2;
    int kq = t & 3;
    bool valid = (rowbase + r) < NN;
    const float* Arow = A + (size_t)(rowbase + r) * FDIM;
#pragma unroll
    for (int q = 0; q < 8; ++q) {
      int k0 = kq * 4 + q * 16;
      float4 v = valid ? *(const float4*)(Arow + k0) : make_float4(0.f, 0.f, 0.f, 0.f);
      aT[(k0 + 0) * 68 + r] = v.x;
      aT[(k0 + 1) * 68 + r] = v.y;
      aT[(k0 + 2) * 68 + r] = v.z;
      aT[(k0 + 3) * 68 + r] = v.w;
    }
  }
  __syncthreads();

  int w = t >> 6;
  int lane = t & 63;
  int rg = lane >> 5;
  int c = lane & 31;
  int rbase = w * 16 + rg * 8;

  float acc[8][4];
#pragma unroll
  for (int r = 0; r < 8; ++r)
#pragma unroll
    for (int j = 0; j < 4; ++j) acc[r][j] = 0.f;

#pragma unroll 4
  for (int k = 0; k < 128; ++k) {
    float4 bv = *(const float4*)(W + k * FDIM + c * 4);
    const float* ap = &aT[k * 68 + rbase];
    float4 a0 = *(const float4*)(ap);
    float4 a1 = *(const float4*)(ap + 4);
    float ar[8] = {a0.x, a0.y, a0.z, a0.w, a1.x, a1.y, a1.z, a1.w};
#pragma unroll
    for (int r = 0; r < 8; ++r) {
      acc[r][0] += ar[r] * bv.x;
      acc[r][1] += ar[r] * bv.y;
      acc[r][2] += ar[r] * bv.z;
      acc[r][3] += ar[r] * bv.w;
    }
  }

  float4 b4 = *(const float4*)(bias + c * 4);
#pragma unroll
  for (int r = 0; r < 8; ++r) {
    int row = rowbase + rbase + r;
    if (row < NN) {
      float4 o;
      o.x = fmaxf(acc[r][0] + b4.x, 0.f);
      o.y = fmaxf(acc[r][1] + b4.y, 0.f);
      o.z = fmaxf(acc[r][2] + b4.z, 0.f);
      o.w = fmaxf(acc[r][3] + b4.w, 0.f);
      *(float4*)(out + (size_t)row * FDIM + c * 4) = o;
    }
  }
}

// ---------------- global sum pool (batching is sorted) ----------------
__device__ int lower_bound_dev(const int* __restrict__ arr, int n, int val) {
  int lo = 0, hi = n;
  while (lo < hi) {
    int mid = (lo + hi) >> 1;
    if (arr[mid] < val) lo = mid + 1; else hi = mid;
  }
  return lo;
}

__global__ __launch_bounds__(128) void pool_kernel(const float* __restrict__ x,
                                                   const int* __restrict__ batching,
                                                   float* __restrict__ g) {
  __shared__ int se, ee;
  int gid = blockIdx.x, t = threadIdx.x;
  if (t == 0) {
    se = lower_bound_dev(batching, NN, gid);
    ee = lower_bound_dev(batching, NN, gid + 1);
  }
  __syncthreads();
  float acc = 0.f;
  for (int n = se; n < ee; ++n) acc += x[(size_t)n * FDIM + t];
  g[(size_t)gid * FDIM + t] = acc;
}

// ---------------- FC1 + FC2 + softmax ----------------
__global__ __launch_bounds__(64) void head_kernel(const float* __restrict__ g,
                                                  const float* __restrict__ Wf1,
                                                  const float* __restrict__ bf1,
                                                  const float* __restrict__ Wf2,
                                                  const float* __restrict__ bf2,
                                                  float* __restrict__ out) {
  __shared__ float gl[128];
  __shared__ float hl[64];
  __shared__ float ol[10];
  __shared__ float red[2];
  int gid = blockIdx.x, t = threadIdx.x;
  gl[t] = g[(size_t)gid * FDIM + t];
  gl[t + 64] = g[(size_t)gid * FDIM + 64 + t];
  __syncthreads();
  float h = bf1[t];
  for (int f = 0; f < 128; ++f) h += gl[f] * Wf1[f * NFC1 + t];
  hl[t] = h;
  __syncthreads();
  if (t < NFC2) {
    float o = bf2[t];
    for (int i = 0; i < NFC1; ++i) o += hl[i] * Wf2[i * NFC2 + t];
    ol[t] = o;
  }
  __syncthreads();
  if (t == 0) {
    float m = ol[0];
    for (int i = 1; i < NFC2; ++i) m = fmaxf(m, ol[i]);
    float s = 0.f;
    for (int i = 0; i < NFC2; ++i) s += expf(ol[i] - m);
    red[0] = m;
    red[1] = s;
  }
  __syncthreads();
  if (t < NFC2) out[(size_t)gid * NFC2 + t] = expf(ol[t] - red[0]) / red[1];
}

extern "C" void kernel_launch(void* const* d_in, const int* in_sizes, int n_in,
                              void* d_out, int out_size, void* d_ws, size_t ws_size,
                              hipStream_t stream) {
  const float* node_attr = (const float*)d_in[0];
  const float* Wc = (const float*)d_in[1];   // [3][128][128]
  const float* bc = (const float*)d_in[2];   // [3][128]
  const float* Wf1 = (const float*)d_in[3];  // [128][64]
  const float* bf1 = (const float*)d_in[4];
  const float* Wf2 = (const float*)d_in[5];  // [64][10]
  const float* bf2 = (const float*)d_in[6];
  const int* src = (const int*)d_in[7];
  const int* dst = (const int*)d_in[8];
  const int* batching = (const int*)d_in[9];
  float* out = (float*)d_out;

  char* wsp = (char*)d_ws;
  size_t off = 0;
  auto alloc = [&](size_t bytes) -> void* {
    void* p = wsp + off;
    off += (bytes + 255) & ~(size_t)255;
    return p;
  };
  int* row_off = (int*)alloc((size_t)(NN + 1) * sizeof(int));
  int* gcursor = (int*)alloc(NBUCK * sizeof(int));
  int* bbase = (int*)alloc(NBUCK * sizeof(int));
  int* esrc = (int*)alloc((size_t)NE * sizeof(int));
  float* bufA = (float*)alloc((size_t)NN * FDIM * sizeof(float));
  float* bufB = (float*)alloc((size_t)NN * FDIM * sizeof(float));
  float* gbuf = (float*)alloc((size_t)NG * FDIM * sizeof(float));
  // staging (16 MB) aliases bufB: dead before agg-1 writes bufB
  int* staging = (int*)bufB;

  // CSR build via 2-level counting sort
  hipMemsetAsync(gcursor, 0, NBUCK * sizeof(int), stream);
  bin_kernel<<<(NE + 256 * EPB - 1) / (256 * EPB), 256, 0, stream>>>(src, dst, gcursor, staging);
  bucket_scan<<<1, 256, 0, stream>>>(gcursor, bbase);
  build_kernel<<<NBUCK, 256, 0, stream>>>(staging, gcursor, bbase, row_off, esrc);

  // conv layers
  agg_csr<<<NN / 4, 256, 0, stream>>>((const float4*)node_attr, row_off, esrc, (float4*)bufB);
  gemm_bias_relu<<<(NN + 63) / 64, 256, 0, stream>>>(bufB, Wc, bc, bufA);
  agg_csr<<<NN / 4, 256, 0, stream>>>((const float4*)bufA, row_off, esrc, (float4*)bufB);
  gemm_bias_relu<<<(NN + 63) / 64, 256, 0, stream>>>(bufB, Wc + 16384, bc + 128, bufA);
  agg_csr<<<NN / 4, 256, 0, stream>>>((const float4*)bufA, row_off, esrc, (float4*)bufB);
  gemm_bias_relu<<<(NN + 63) / 64, 256, 0, stream>>>(bufB, Wc + 32768, bc + 256, bufA);

  // pool + head
  pool_kernel<<<NG, 128, 0, stream>>>(bufA, batching, gbuf);
  head_kernel<<<NG, 64, 0, stream>>>(gbuf, Wf1, bf1, Wf2, bf2, out);
}

// Round 3
// 1027.751 us; speedup vs baseline: 1.2698x; 1.0029x over previous
//
#include <hip/hip_runtime.h>
#include <math.h>

#define NN 100000
#define NE 3200000
#define NG 1024
#define FDIM 128
#define NFC1 64
#define NFC2 10

#define BSHIFT 9
#define NBUCK 196   // ceil(NN/512)
#define CAP 20480   // mean 16384, sigma ~127 -> 32-sigma headroom
#define EPB 16      // edges per thread in bin_kernel

// ---------------- pass 1: bin edges into 196 coarse buckets ----------------
// Packed value: (dst & 511) << 17 | src   (src < 2^17, dst_local < 2^9)
__global__ __launch_bounds__(256) void bin_kernel(const int* __restrict__ src,
                                                  const int* __restrict__ dst,
                                                  int* __restrict__ gcursor,
                                                  int* __restrict__ staging) {
  __shared__ int hist[NBUCK];
  __shared__ int base[NBUCK];
  int t = threadIdx.x;
  for (int i = t; i < NBUCK; i += 256) hist[i] = 0;
  __syncthreads();
  size_t e0 = (size_t)blockIdx.x * (256 * EPB);
  int bk[EPB], rank[EPB], val[EPB];
#pragma unroll
  for (int j = 0; j < EPB; ++j) {
    size_t e = e0 + (size_t)j * 256 + t;
    if (e < NE) {
      int d = dst[e];
      int s = src[e];
      bk[j] = d >> BSHIFT;
      val[j] = ((d & 511) << 17) | s;
      rank[j] = atomicAdd(&hist[bk[j]], 1);
    } else {
      bk[j] = -1;
    }
  }
  __syncthreads();
  for (int i = t; i < NBUCK; i += 256) base[i] = atomicAdd(&gcursor[i], hist[i]);
  __syncthreads();
#pragma unroll
  for (int j = 0; j < EPB; ++j) {
    if (bk[j] >= 0) {
      int pos = base[bk[j]] + rank[j];
      if (pos < CAP) staging[(size_t)bk[j] * CAP + pos] = val[j];
    }
  }
}

// ---------------- pass 1.5: exclusive scan of bucket counts ----------------
__global__ __launch_bounds__(256) void bucket_scan(const int* __restrict__ gcursor,
                                                   int* __restrict__ bbase) {
  __shared__ int s[256];
  int t = threadIdx.x;
  int v = (t < NBUCK) ? gcursor[t] : 0;
  s[t] = v;
  __syncthreads();
  for (int st = 1; st < 256; st <<= 1) {
    int u = (t >= st) ? s[t - st] : 0;
    __syncthreads();
    s[t] += u;
    __syncthreads();
  }
  if (t < NBUCK) bbase[t] = s[t] - v;  // exclusive
}

// ---------------- pass 2: per-bucket CSR finalize ----------------
__global__ __launch_bounds__(256) void build_kernel(const int* __restrict__ staging,
                                                    const int* __restrict__ gcursor,
                                                    const int* __restrict__ bbase,
                                                    int* __restrict__ row_off,
                                                    int* __restrict__ esrc) {
  __shared__ int ncnt[512];
  __shared__ int noff[513];
  __shared__ int part[256];
  int b = blockIdx.x, t = threadIdx.x;
  int cnt = gcursor[b];
  int ebase = bbase[b];
  int nbase = b << BSHIFT;
  ncnt[t] = 0;
  ncnt[t + 256] = 0;
  __syncthreads();
  const int* sp = staging + (size_t)b * CAP;
  for (int i = t; i < cnt; i += 256) {
    int dl = sp[i] >> 17;
    atomicAdd(&ncnt[dl], 1);
  }
  __syncthreads();
  int a0 = ncnt[2 * t], a1 = ncnt[2 * t + 1];
  part[t] = a0 + a1;
  __syncthreads();
  for (int st = 1; st < 256; st <<= 1) {
    int u = (t >= st) ? part[t - st] : 0;
    __syncthreads();
    part[t] += u;
    __syncthreads();
  }
  int excl = (t > 0) ? part[t - 1] : 0;
  noff[2 * t] = excl;
  noff[2 * t + 1] = excl + a0;
  if (t == 255) noff[512] = part[255];
  __syncthreads();
  for (int i = t; i <= 512; i += 256) {
    int n = nbase + i;
    if (n <= NN) row_off[n] = ebase + noff[i];
  }
  // reuse ncnt as write cursors
  ncnt[2 * t] = noff[2 * t];
  ncnt[2 * t + 1] = noff[2 * t + 1];
  __syncthreads();
  for (int i = t; i < cnt; i += 256) {
    int v = sp[i];
    int dl = v >> 17;
    int pos = atomicAdd(&ncnt[dl], 1);
    esrc[ebase + pos] = v & 0x1FFFF;
  }
}

// ---------------- edge aggregation (CSR gather), wave-per-node ----------------
// One full wave per node; lane owns floats [2*lane, 2*lane+1] of the 512 B row.
// beg/end/esrc[e] are wave-uniform (readfirstlane -> SGPR / s_load path), so the
// vector memory pipe issues ONLY the row gathers: 8 x global_load_dwordx2 in
// flight per wave (4 KB), no dependent vector index load in the chain.
__global__ __launch_bounds__(256) void agg_csr(const float2* __restrict__ xin,
                                               const int* __restrict__ row_off,
                                               const int* __restrict__ esrc,
                                               float2* __restrict__ aggout) {
  int node = blockIdx.x * 4 + (threadIdx.x >> 6);
  int lane = threadIdx.x & 63;
  int beg = __builtin_amdgcn_readfirstlane(row_off[node]);
  int end = __builtin_amdgcn_readfirstlane(row_off[node + 1]);
  float2 acc = make_float2(0.f, 0.f);
  int e = beg;
  for (; e + 8 <= end; e += 8) {
    int i0 = __builtin_amdgcn_readfirstlane(esrc[e + 0]);
    int i1 = __builtin_amdgcn_readfirstlane(esrc[e + 1]);
    int i2 = __builtin_amdgcn_readfirstlane(esrc[e + 2]);
    int i3 = __builtin_amdgcn_readfirstlane(esrc[e + 3]);
    int i4 = __builtin_amdgcn_readfirstlane(esrc[e + 4]);
    int i5 = __builtin_amdgcn_readfirstlane(esrc[e + 5]);
    int i6 = __builtin_amdgcn_readfirstlane(esrc[e + 6]);
    int i7 = __builtin_amdgcn_readfirstlane(esrc[e + 7]);
    float2 v0 = xin[(size_t)i0 * 64 + lane];
    float2 v1 = xin[(size_t)i1 * 64 + lane];
    float2 v2 = xin[(size_t)i2 * 64 + lane];
    float2 v3 = xin[(size_t)i3 * 64 + lane];
    float2 v4 = xin[(size_t)i4 * 64 + lane];
    float2 v5 = xin[(size_t)i5 * 64 + lane];
    float2 v6 = xin[(size_t)i6 * 64 + lane];
    float2 v7 = xin[(size_t)i7 * 64 + lane];
    acc.x += ((v0.x + v1.x) + (v2.x + v3.x)) + ((v4.x + v5.x) + (v6.x + v7.x));
    acc.y += ((v0.y + v1.y) + (v2.y + v3.y)) + ((v4.y + v5.y) + (v6.y + v7.y));
  }
  for (; e < end; ++e) {
    int i0 = __builtin_amdgcn_readfirstlane(esrc[e]);
    float2 v0 = xin[(size_t)i0 * 64 + lane];
    acc.x += v0.x;
    acc.y += v0.y;
  }
  aggout[(size_t)node * 64 + lane] = acc;
}

// ---------------- fp32 GEMM: out = relu(A[NN,128] @ W[128,128] + bias) ----------------
__global__ __launch_bounds__(256) void gemm_bias_relu(const float* __restrict__ A,
                                                      const float* __restrict__ W,
                                                      const float* __restrict__ bias,
                                                      float* __restrict__ out) {
  __shared__ __align__(16) float aT[128 * 68];
  int t = threadIdx.x;
  int rowbase = blockIdx.x * 64;

  {  // stage 64 rows x 128 k, transposed
    int r = t >> 2;
    int kq = t & 3;
    bool valid = (rowbase + r) < NN;
    const float* Arow = A + (size_t)(rowbase + r) * FDIM;
#pragma unroll
    for (int q = 0; q < 8; ++q) {
      int k0 = kq * 4 + q * 16;
      float4 v = valid ? *(const float4*)(Arow + k0) : make_float4(0.f, 0.f, 0.f, 0.f);
      aT[(k0 + 0) * 68 + r] = v.x;
      aT[(k0 + 1) * 68 + r] = v.y;
      aT[(k0 + 2) * 68 + r] = v.z;
      aT[(k0 + 3) * 68 + r] = v.w;
    }
  }
  __syncthreads();

  int w = t >> 6;
  int lane = t & 63;
  int rg = lane >> 5;
  int c = lane & 31;
  int rbase = w * 16 + rg * 8;

  float acc[8][4];
#pragma unroll
  for (int r = 0; r < 8; ++r)
#pragma unroll
    for (int j = 0; j < 4; ++j) acc[r][j] = 0.f;

#pragma unroll 4
  for (int k = 0; k < 128; ++k) {
    float4 bv = *(const float4*)(W + k * FDIM + c * 4);
    const float* ap = &aT[k * 68 + rbase];
    float4 a0 = *(const float4*)(ap);
    float4 a1 = *(const float4*)(ap + 4);
    float ar[8] = {a0.x, a0.y, a0.z, a0.w, a1.x, a1.y, a1.z, a1.w};
#pragma unroll
    for (int r = 0; r < 8; ++r) {
      acc[r][0] += ar[r] * bv.x;
      acc[r][1] += ar[r] * bv.y;
      acc[r][2] += ar[r] * bv.z;
      acc[r][3] += ar[r] * bv.w;
    }
  }

  float4 b4 = *(const float4*)(bias + c * 4);
#pragma unroll
  for (int r = 0; r < 8; ++r) {
    int row = rowbase + rbase + r;
    if (row < NN) {
      float4 o;
      o.x = fmaxf(acc[r][0] + b4.x, 0.f);
      o.y = fmaxf(acc[r][1] + b4.y, 0.f);
      o.z = fmaxf(acc[r][2] + b4.z, 0.f);
      o.w = fmaxf(acc[r][3] + b4.w, 0.f);
      *(float4*)(out + (size_t)row * FDIM + c * 4) = o;
    }
  }
}

// ---------------- global sum pool (batching is sorted) ----------------
__device__ int lower_bound_dev(const int* __restrict__ arr, int n, int val) {
  int lo = 0, hi = n;
  while (lo < hi) {
    int mid = (lo + hi) >> 1;
    if (arr[mid] < val) lo = mid + 1; else hi = mid;
  }
  return lo;
}

__global__ __launch_bounds__(128) void pool_kernel(const float* __restrict__ x,
                                                   const int* __restrict__ batching,
                                                   float* __restrict__ g) {
  __shared__ int se, ee;
  int gid = blockIdx.x, t = threadIdx.x;
  if (t == 0) {
    se = lower_bound_dev(batching, NN, gid);
    ee = lower_bound_dev(batching, NN, gid + 1);
  }
  __syncthreads();
  float acc = 0.f;
  for (int n = se; n < ee; ++n) acc += x[(size_t)n * FDIM + t];
  g[(size_t)gid * FDIM + t] = acc;
}

// ---------------- FC1 + FC2 + softmax ----------------
__global__ __launch_bounds__(64) void head_kernel(const float* __restrict__ g,
                                                  const float* __restrict__ Wf1,
                                                  const float* __restrict__ bf1,
                                                  const float* __restrict__ Wf2,
                                                  const float* __restrict__ bf2,
                                                  float* __restrict__ out) {
  __shared__ float gl[128];
  __shared__ float hl[64];
  __shared__ float ol[10];
  __shared__ float red[2];
  int gid = blockIdx.x, t = threadIdx.x;
  gl[t] = g[(size_t)gid * FDIM + t];
  gl[t + 64] = g[(size_t)gid * FDIM + 64 + t];
  __syncthreads();
  float h = bf1[t];
  for (int f = 0; f < 128; ++f) h += gl[f] * Wf1[f * NFC1 + t];
  hl[t] = h;
  __syncthreads();
  if (t < NFC2) {
    float o = bf2[t];
    for (int i = 0; i < NFC1; ++i) o += hl[i] * Wf2[i * NFC2 + t];
    ol[t] = o;
  }
  __syncthreads();
  if (t == 0) {
    float m = ol[0];
    for (int i = 1; i < NFC2; ++i) m = fmaxf(m, ol[i]);
    float s = 0.f;
    for (int i = 0; i < NFC2; ++i) s += expf(ol[i] - m);
    red[0] = m;
    red[1] = s;
  }
  __syncthreads();
  if (t < NFC2) out[(size_t)gid * NFC2 + t] = expf(ol[t] - red[0]) / red[1];
}

extern "C" void kernel_launch(void* const* d_in, const int* in_sizes, int n_in,
                              void* d_out, int out_size, void* d_ws, size_t ws_size,
                              hipStream_t stream) {
  const float* node_attr = (const float*)d_in[0];
  const float* Wc = (const float*)d_in[1];   // [3][128][128]
  const float* bc = (const float*)d_in[2];   // [3][128]
  const float* Wf1 = (const float*)d_in[3];  // [128][64]
  const float* bf1 = (const float*)d_in[4];
  const float* Wf2 = (const float*)d_in[5];  // [64][10]
  const float* bf2 = (const float*)d_in[6];
  const int* src = (const int*)d_in[7];
  const int* dst = (const int*)d_in[8];
  const int* batching = (const int*)d_in[9];
  float* out = (float*)d_out;

  char* wsp = (char*)d_ws;
  size_t off = 0;
  auto alloc = [&](size_t bytes) -> void* {
    void* p = wsp + off;
    off += (bytes + 255) & ~(size_t)255;
    return p;
  };
  int* row_off = (int*)alloc((size_t)(NN + 1) * sizeof(int));
  int* gcursor = (int*)alloc(NBUCK * sizeof(int));
  int* bbase = (int*)alloc(NBUCK * sizeof(int));
  int* esrc = (int*)alloc((size_t)NE * sizeof(int));
  float* bufA = (float*)alloc((size_t)NN * FDIM * sizeof(float));
  float* bufB = (float*)alloc((size_t)NN * FDIM * sizeof(float));
  float* gbuf = (float*)alloc((size_t)NG * FDIM * sizeof(float));
  // staging (16 MB) aliases bufB: dead before agg-1 writes bufB
  int* staging = (int*)bufB;

  // CSR build via 2-level counting sort
  hipMemsetAsync(gcursor, 0, NBUCK * sizeof(int), stream);
  bin_kernel<<<(NE + 256 * EPB - 1) / (256 * EPB), 256, 0, stream>>>(src, dst, gcursor, staging);
  bucket_scan<<<1, 256, 0, stream>>>(gcursor, bbase);
  build_kernel<<<NBUCK, 256, 0, stream>>>(staging, gcursor, bbase, row_off, esrc);

  // conv layers
  agg_csr<<<NN / 4, 256, 0, stream>>>((const float2*)node_attr, row_off, esrc, (float2*)bufB);
  gemm_bias_relu<<<(NN + 63) / 64, 256, 0, stream>>>(bufB, Wc, bc, bufA);
  agg_csr<<<NN / 4, 256, 0, stream>>>((const float2*)bufA, row_off, esrc, (float2*)bufB);
  gemm_bias_relu<<<(NN + 63) / 64, 256, 0, stream>>>(bufB, Wc + 16384, bc + 128, bufA);
  agg_csr<<<NN / 4, 256, 0, stream>>>((const float2*)bufA, row_off, esrc, (float2*)bufB);
  gemm_bias_relu<<<(NN + 63) / 64, 256, 0, stream>>>(bufB, Wc + 32768, bc + 256, bufA);

  // pool + head
  pool_kernel<<<NG, 128, 0, stream>>>(bufA, batching, gbuf);
  head_kernel<<<NG, 64, 0, stream>>>(gbuf, Wf1, bf1, Wf2, bf2, out);
}

// Round 4
// 1007.877 us; speedup vs baseline: 1.2948x; 1.0197x over previous
//
#include <hip/hip_runtime.h>
#include <math.h>

#define NN 100000
#define NE 3200000
#define NG 1024
#define FDIM 128
#define NFC1 64
#define NFC2 10

#define BSHIFT 9
#define NBUCK 196   // ceil(NN/512)
#define CAP 20480   // mean 16384, sigma ~127 -> 32-sigma headroom
#define EPB 16      // edges per thread in bin_kernel

// ---------------- pass 1: bin edges into 196 coarse buckets ----------------
// Packed value: (dst & 511) << 17 | src   (src < 2^17, dst_local < 2^9)
__global__ __launch_bounds__(256) void bin_kernel(const int* __restrict__ src,
                                                  const int* __restrict__ dst,
                                                  int* __restrict__ gcursor,
                                                  int* __restrict__ staging) {
  __shared__ int hist[NBUCK];
  __shared__ int base[NBUCK];
  int t = threadIdx.x;
  for (int i = t; i < NBUCK; i += 256) hist[i] = 0;
  __syncthreads();
  size_t e0 = (size_t)blockIdx.x * (256 * EPB);
  int bk[EPB], rank[EPB], val[EPB];
#pragma unroll
  for (int j = 0; j < EPB; ++j) {
    size_t e = e0 + (size_t)j * 256 + t;
    if (e < NE) {
      int d = dst[e];
      int s = src[e];
      bk[j] = d >> BSHIFT;
      val[j] = ((d & 511) << 17) | s;
      rank[j] = atomicAdd(&hist[bk[j]], 1);
    } else {
      bk[j] = -1;
    }
  }
  __syncthreads();
  for (int i = t; i < NBUCK; i += 256) base[i] = atomicAdd(&gcursor[i], hist[i]);
  __syncthreads();
#pragma unroll
  for (int j = 0; j < EPB; ++j) {
    if (bk[j] >= 0) {
      int pos = base[bk[j]] + rank[j];
      if (pos < CAP) staging[(size_t)bk[j] * CAP + pos] = val[j];
    }
  }
}

// ---------------- pass 2: per-bucket CSR finalize (scan fused in) ----------------
__global__ __launch_bounds__(256) void build_kernel(const int* __restrict__ staging,
                                                    const int* __restrict__ gcursor,
                                                    int* __restrict__ row_off,
                                                    int* __restrict__ esrc) {
  __shared__ int ncnt[512];
  __shared__ int noff[513];
  __shared__ int part[256];
  __shared__ int sscan[256];
  int b = blockIdx.x, t = threadIdx.x;
  // inline exclusive scan of bucket counts to get this block's edge base
  int gv = (t < NBUCK) ? gcursor[t] : 0;
  sscan[t] = gv;
  __syncthreads();
  for (int st = 1; st < 256; st <<= 1) {
    int u = (t >= st) ? sscan[t - st] : 0;
    __syncthreads();
    sscan[t] += u;
    __syncthreads();
  }
  int cnt = gcursor[b];
  int ebase = sscan[b] - cnt;  // exclusive prefix
  int nbase = b << BSHIFT;
  ncnt[t] = 0;
  ncnt[t + 256] = 0;
  __syncthreads();
  const int* sp = staging + (size_t)b * CAP;
  for (int i = t; i < cnt; i += 256) {
    int dl = sp[i] >> 17;
    atomicAdd(&ncnt[dl], 1);
  }
  __syncthreads();
  int a0 = ncnt[2 * t], a1 = ncnt[2 * t + 1];
  part[t] = a0 + a1;
  __syncthreads();
  for (int st = 1; st < 256; st <<= 1) {
    int u = (t >= st) ? part[t - st] : 0;
    __syncthreads();
    part[t] += u;
    __syncthreads();
  }
  int excl = (t > 0) ? part[t - 1] : 0;
  noff[2 * t] = excl;
  noff[2 * t + 1] = excl + a0;
  if (t == 255) noff[512] = part[255];
  __syncthreads();
  for (int i = t; i <= 512; i += 256) {
    int n = nbase + i;
    if (n <= NN) row_off[n] = ebase + noff[i];
  }
  // reuse ncnt as write cursors
  ncnt[2 * t] = noff[2 * t];
  ncnt[2 * t + 1] = noff[2 * t + 1];
  __syncthreads();
  for (int i = t; i < cnt; i += 256) {
    int v = sp[i];
    int dl = v >> 17;
    int pos = atomicAdd(&ncnt[dl], 1);
    esrc[ebase + pos] = v & 0x1FFFF;
  }
}

// ---------------- fused conv layer: out = relu(gather(xin)@W + bias) ----------------
// 512 threads = 8 waves; 64 dst nodes per block.
// Phase 1: wave w gathers+accumulates nodes w*8..w*8+7 (wave-uniform indices,
//   8 x 512B rows in flight), writes its rows transposed into LDS aT.
// Phase 2: wave w GEMMs its own 8 rows x 128 cols from aT (stride 68, b128
//   broadcast reads) with W streamed from L1; relu+bias; float4 store.
__global__ __launch_bounds__(512) void conv_fused(const float2* __restrict__ xin,
                                                  const int* __restrict__ row_off,
                                                  const int* __restrict__ esrc,
                                                  const float* __restrict__ W,
                                                  const float* __restrict__ bias,
                                                  float* __restrict__ out) {
  __shared__ __align__(16) float aT[128 * 68];
  int t = threadIdx.x;
  int w = t >> 6;
  int lane = t & 63;
  int nodebase = blockIdx.x * 64;

  // ---- phase 1: gather-aggregate 8 nodes for this wave ----
  for (int i = 0; i < 8; ++i) {
    int r = w * 8 + i;
    int node = nodebase + r;
    int beg = 0, end = 0;
    if (node < NN) {
      beg = __builtin_amdgcn_readfirstlane(row_off[node]);
      end = __builtin_amdgcn_readfirstlane(row_off[node + 1]);
    }
    float2 acc = make_float2(0.f, 0.f);
    int e = beg;
    for (; e + 8 <= end; e += 8) {
      int i0 = __builtin_amdgcn_readfirstlane(esrc[e + 0]);
      int i1 = __builtin_amdgcn_readfirstlane(esrc[e + 1]);
      int i2 = __builtin_amdgcn_readfirstlane(esrc[e + 2]);
      int i3 = __builtin_amdgcn_readfirstlane(esrc[e + 3]);
      int i4 = __builtin_amdgcn_readfirstlane(esrc[e + 4]);
      int i5 = __builtin_amdgcn_readfirstlane(esrc[e + 5]);
      int i6 = __builtin_amdgcn_readfirstlane(esrc[e + 6]);
      int i7 = __builtin_amdgcn_readfirstlane(esrc[e + 7]);
      float2 v0 = xin[(size_t)i0 * 64 + lane];
      float2 v1 = xin[(size_t)i1 * 64 + lane];
      float2 v2 = xin[(size_t)i2 * 64 + lane];
      float2 v3 = xin[(size_t)i3 * 64 + lane];
      float2 v4 = xin[(size_t)i4 * 64 + lane];
      float2 v5 = xin[(size_t)i5 * 64 + lane];
      float2 v6 = xin[(size_t)i6 * 64 + lane];
      float2 v7 = xin[(size_t)i7 * 64 + lane];
      acc.x += ((v0.x + v1.x) + (v2.x + v3.x)) + ((v4.x + v5.x) + (v6.x + v7.x));
      acc.y += ((v0.y + v1.y) + (v2.y + v3.y)) + ((v4.y + v5.y) + (v6.y + v7.y));
    }
    for (; e < end; ++e) {
      int i0 = __builtin_amdgcn_readfirstlane(esrc[e]);
      float2 v0 = xin[(size_t)i0 * 64 + lane];
      acc.x += v0.x;
      acc.y += v0.y;
    }
    aT[(2 * lane + 0) * 68 + r] = acc.x;
    aT[(2 * lane + 1) * 68 + r] = acc.y;
  }
  __syncthreads();

  // ---- phase 2: GEMM 64x128 tile ----
  int rg = lane >> 5;       // 0..1
  int c = lane & 31;        // cols 4c..4c+3
  int rbase = w * 8 + rg * 4;

  float acc[4][4];
#pragma unroll
  for (int r = 0; r < 4; ++r)
#pragma unroll
    for (int j = 0; j < 4; ++j) acc[r][j] = 0.f;

#pragma unroll 4
  for (int k = 0; k < 128; ++k) {
    float4 bv = *(const float4*)(W + k * FDIM + c * 4);
    float4 a0 = *(const float4*)(&aT[k * 68 + rbase]);
    float ar[4] = {a0.x, a0.y, a0.z, a0.w};
#pragma unroll
    for (int r = 0; r < 4; ++r) {
      acc[r][0] += ar[r] * bv.x;
      acc[r][1] += ar[r] * bv.y;
      acc[r][2] += ar[r] * bv.z;
      acc[r][3] += ar[r] * bv.w;
    }
  }

  float4 b4 = *(const float4*)(bias + c * 4);
#pragma unroll
  for (int r = 0; r < 4; ++r) {
    int row = nodebase + rbase + r;
    if (row < NN) {
      float4 o;
      o.x = fmaxf(acc[r][0] + b4.x, 0.f);
      o.y = fmaxf(acc[r][1] + b4.y, 0.f);
      o.z = fmaxf(acc[r][2] + b4.z, 0.f);
      o.w = fmaxf(acc[r][3] + b4.w, 0.f);
      *(float4*)(out + (size_t)row * FDIM + c * 4) = o;
    }
  }
}

// ---------------- fused global pool + FC1 + FC2 + softmax ----------------
__device__ int lower_bound_dev(const int* __restrict__ arr, int n, int val) {
  int lo = 0, hi = n;
  while (lo < hi) {
    int mid = (lo + hi) >> 1;
    if (arr[mid] < val) lo = mid + 1; else hi = mid;
  }
  return lo;
}

__global__ __launch_bounds__(128) void pool_head(const float* __restrict__ x,
                                                 const int* __restrict__ batching,
                                                 const float* __restrict__ Wf1,
                                                 const float* __restrict__ bf1,
                                                 const float* __restrict__ Wf2,
                                                 const float* __restrict__ bf2,
                                                 float* __restrict__ out) {
  __shared__ int se, ee;
  __shared__ float gl[128];
  __shared__ float hl[64];
  __shared__ float ol[10];
  __shared__ float red[2];
  int gid = blockIdx.x, t = threadIdx.x;
  if (t == 0) {
    se = lower_bound_dev(batching, NN, gid);
    ee = lower_bound_dev(batching, NN, gid + 1);
  }
  __syncthreads();
  float acc = 0.f;
  for (int n = se; n < ee; ++n) acc += x[(size_t)n * FDIM + t];
  gl[t] = acc;
  __syncthreads();
  if (t < NFC1) {
    float h = bf1[t];
    for (int f = 0; f < 128; ++f) h += gl[f] * Wf1[f * NFC1 + t];
    hl[t] = h;
  }
  __syncthreads();
  if (t < NFC2) {
    float o = bf2[t];
    for (int i = 0; i < NFC1; ++i) o += hl[i] * Wf2[i * NFC2 + t];
    ol[t] = o;
  }
  __syncthreads();
  if (t == 0) {
    float m = ol[0];
    for (int i = 1; i < NFC2; ++i) m = fmaxf(m, ol[i]);
    float s = 0.f;
    for (int i = 0; i < NFC2; ++i) s += expf(ol[i] - m);
    red[0] = m;
    red[1] = s;
  }
  __syncthreads();
  if (t < NFC2) out[(size_t)gid * NFC2 + t] = expf(ol[t] - red[0]) / red[1];
}

extern "C" void kernel_launch(void* const* d_in, const int* in_sizes, int n_in,
                              void* d_out, int out_size, void* d_ws, size_t ws_size,
                              hipStream_t stream) {
  const float* node_attr = (const float*)d_in[0];
  const float* Wc = (const float*)d_in[1];   // [3][128][128]
  const float* bc = (const float*)d_in[2];   // [3][128]
  const float* Wf1 = (const float*)d_in[3];  // [128][64]
  const float* bf1 = (const float*)d_in[4];
  const float* Wf2 = (const float*)d_in[5];  // [64][10]
  const float* bf2 = (const float*)d_in[6];
  const int* src = (const int*)d_in[7];
  const int* dst = (const int*)d_in[8];
  const int* batching = (const int*)d_in[9];
  float* out = (float*)d_out;

  char* wsp = (char*)d_ws;
  size_t off = 0;
  auto alloc = [&](size_t bytes) -> void* {
    void* p = wsp + off;
    off += (bytes + 255) & ~(size_t)255;
    return p;
  };
  int* row_off = (int*)alloc((size_t)(NN + 1) * sizeof(int));
  int* gcursor = (int*)alloc(NBUCK * sizeof(int));
  int* esrc = (int*)alloc((size_t)NE * sizeof(int));
  float* bufA = (float*)alloc((size_t)NN * FDIM * sizeof(float));
  float* bufB = (float*)alloc((size_t)NN * FDIM * sizeof(float));
  // staging (16.1 MB) aliases bufB: staging is dead before layer-2 writes bufB
  int* staging = (int*)bufB;

  // CSR build via 2-level counting sort
  hipMemsetAsync(gcursor, 0, NBUCK * sizeof(int), stream);
  bin_kernel<<<(NE + 256 * EPB - 1) / (256 * EPB), 256, 0, stream>>>(src, dst, gcursor, staging);
  build_kernel<<<NBUCK, 256, 0, stream>>>(staging, gcursor, row_off, esrc);

  // fused conv layers: gather -> LDS -> GEMM -> relu -> store
  conv_fused<<<(NN + 63) / 64, 512, 0, stream>>>((const float2*)node_attr, row_off, esrc,
                                                 Wc, bc, bufA);
  conv_fused<<<(NN + 63) / 64, 512, 0, stream>>>((const float2*)bufA, row_off, esrc,
                                                 Wc + 16384, bc + 128, bufB);
  conv_fused<<<(NN + 63) / 64, 512, 0, stream>>>((const float2*)bufB, row_off, esrc,
                                                 Wc + 32768, bc + 256, bufA);

  // fused pool + head
  pool_head<<<NG, 128, 0, stream>>>(bufA, batching, Wf1, bf1, Wf2, bf2, out);
}